// Round 3
// baseline (521.250 us; speedup 1.0000x reference)
//
#include <hip/hip_runtime.h>
#include <hip/hip_bf16.h>
#include <math.h>

typedef __attribute__((ext_vector_type(8))) short bf16x8;
typedef __attribute__((ext_vector_type(4))) float f32x4;

// Problem constants
static constexpr int kB = 4, kN = 1024, kC = 2048, kH = 16, kD = 128;
static constexpr int kM = kB * kN;   // 4096 rows of x
static constexpr int k3C = 3 * kC;   // 6144

__device__ __forceinline__ short f2bf(float f) {
  unsigned u = __float_as_uint(f);
  u = (u + 0x7FFFu + ((u >> 16) & 1u)) >> 16;   // RNE
  return (short)u;
}

// ---------------- cast fp32 -> bf16 ----------------
__global__ __launch_bounds__(256) void cast_f32_bf16(const float* __restrict__ in,
                                                     short* __restrict__ out, int n4) {
  int stride = gridDim.x * blockDim.x;
  for (int i = blockIdx.x * blockDim.x + threadIdx.x; i < n4; i += stride) {
    float4 v = reinterpret_cast<const float4*>(in)[i];
    short4 o = make_short4(f2bf(v.x), f2bf(v.y), f2bf(v.z), f2bf(v.w));
    reinterpret_cast<short4*>(out)[i] = o;
  }
}

// ---------------- GEMM C[m,n] = sum_k A[m,k]*Bt[n,k] + bias[n] ----------------
// m97 structure: 128x128 tile, BK=32, 4 waves (2x2 of 64x64), global_load_lds w=16.
// EPI 0: QKV epilogue -> bf16: cols <4096 go to qk[m*4096+col]; cols >=4096 (v) are
//        scattered transposed into vT[(b*2048 + hd)*1024 + pos].
// EPI 1: proj epilogue -> fp32 out[m*N+col].
template <int EPI>
__global__ __launch_bounds__(256) void gemm_bt(const short* __restrict__ A,
                                               const short* __restrict__ Bt,
                                               const float* __restrict__ bias,
                                               void* __restrict__ out0,
                                               short* __restrict__ vT,
                                               int M, int N, int K) {
  __shared__ short As[128 * 32];
  __shared__ short Bs[128 * 32];
  const int lane = threadIdx.x & 63;
  const int wid = threadIdx.x >> 6;
  const int row0 = blockIdx.x * 128;
  const int col0 = blockIdx.y * 128;
  const int wrow = (wid >> 1) * 64;
  const int wcol = (wid & 1) * 64;
  f32x4 acc[4][4] = {};

  // staging source: wave wid covers rows [wid*32, wid*32+32), 2 instrs of 16 rows each.
  // lane l -> row base+(l>>2), shorts offset (l&3)*8  (== lane*16B linear in LDS)
  const short* Ag0 = A + (size_t)(row0 + wid * 32 + (lane >> 2)) * K + (lane & 3) * 8;
  const short* Bg0 = Bt + (size_t)(col0 + wid * 32 + (lane >> 2)) * K + (lane & 3) * 8;

  for (int k0 = 0; k0 < K; k0 += 32) {
    __builtin_amdgcn_global_load_lds(
        (const __attribute__((address_space(1))) void*)(Ag0 + k0),
        (__attribute__((address_space(3))) void*)&As[(wid * 32) * 32], 16, 0, 0);
    __builtin_amdgcn_global_load_lds(
        (const __attribute__((address_space(1))) void*)(Ag0 + 16 * (size_t)K + k0),
        (__attribute__((address_space(3))) void*)&As[(wid * 32 + 16) * 32], 16, 0, 0);
    __builtin_amdgcn_global_load_lds(
        (const __attribute__((address_space(1))) void*)(Bg0 + k0),
        (__attribute__((address_space(3))) void*)&Bs[(wid * 32) * 32], 16, 0, 0);
    __builtin_amdgcn_global_load_lds(
        (const __attribute__((address_space(1))) void*)(Bg0 + 16 * (size_t)K + k0),
        (__attribute__((address_space(3))) void*)&Bs[(wid * 32 + 16) * 32], 16, 0, 0);
    __syncthreads();

    bf16x8 af[4], bfr[4];
#pragma unroll
    for (int mt = 0; mt < 4; ++mt)
      af[mt] = *(const bf16x8*)&As[(wrow + mt * 16 + (lane & 15)) * 32 + (lane >> 4) * 8];
#pragma unroll
    for (int nt = 0; nt < 4; ++nt)
      bfr[nt] = *(const bf16x8*)&Bs[(wcol + nt * 16 + (lane & 15)) * 32 + (lane >> 4) * 8];
#pragma unroll
    for (int mt = 0; mt < 4; ++mt)
#pragma unroll
      for (int nt = 0; nt < 4; ++nt)
        acc[mt][nt] = __builtin_amdgcn_mfma_f32_16x16x32_bf16(af[mt], bfr[nt], acc[mt][nt], 0, 0, 0);
    __syncthreads();
  }

  if (EPI == 0) {
    short* qk = (short*)out0;
#pragma unroll
    for (int mt = 0; mt < 4; ++mt) {
#pragma unroll
      for (int nt = 0; nt < 4; ++nt) {
        int col = col0 + wcol + nt * 16 + (lane & 15);
        float bv = bias[col];
#pragma unroll
        for (int r = 0; r < 4; ++r) {
          int row = row0 + wrow + mt * 16 + (lane >> 4) * 4 + r;
          float v = acc[mt][nt][r] + bv;
          if (col < 4096) {
            qk[(size_t)row * 4096 + col] = f2bf(v);
          } else {
            int b = row >> 10, pos = row & 1023;
            int hd = col - 4096;  // h*128+d
            vT[((size_t)b * 2048 + hd) * 1024 + pos] = f2bf(v);
          }
        }
      }
    }
  } else {
    float* out = (float*)out0;
#pragma unroll
    for (int mt = 0; mt < 4; ++mt) {
#pragma unroll
      for (int nt = 0; nt < 4; ++nt) {
        int col = col0 + wcol + nt * 16 + (lane & 15);
        float bv = bias[col];
#pragma unroll
        for (int r = 0; r < 4; ++r) {
          int row = row0 + wrow + mt * 16 + (lane >> 4) * 4 + r;
          out[(size_t)row * N + col] = acc[mt][nt][r] + bv;
        }
      }
    }
  }
}

// ---------------- flash attention ----------------
// grid: (N/64, B*H). Block = 4 waves; wave w handles 16 q-rows.
// qk layout: [4096][4096] bf16 (q cols 0..2047, k cols 2048..4095), head h at h*128.
// vT layout: [B*H*128][1024] bf16 (vT[(bh*128+d)*1024 + pos]).
// att output: [4096][2048] bf16 (rows b*1024+n, cols h*128+d).
__global__ __launch_bounds__(256) void attn_kernel(const short* __restrict__ qk,
                                                   const short* __restrict__ vT,
                                                   short* __restrict__ att) {
  __shared__ __align__(16) short P[4][16][40];  // per-wave P tile, stride 40 for bank spread
  const int lane = threadIdx.x & 63;
  const int wid = threadIdx.x >> 6;
  const int bh = blockIdx.y;
  const int b = bh >> 4, h = bh & 15;
  const int q0 = blockIdx.x * 64 + wid * 16;

  const short* qbase = qk + (size_t)(b * 1024) * 4096 + h * 128;
  const short* kbase = qbase + 2048;
  const short* vbase = vT + (size_t)bh * 128 * 1024;

  // hoist Q fragments (16 rows x 128 d)
  bf16x8 qf[4];
  {
    const int qrow = q0 + (lane & 15);
#pragma unroll
    for (int dc = 0; dc < 4; ++dc)
      qf[dc] = *(const bf16x8*)&qbase[(size_t)qrow * 4096 + dc * 32 + (lane >> 4) * 8];
  }

  float m_r[4], l_r[4];
#pragma unroll
  for (int r = 0; r < 4; ++r) { m_r[r] = -INFINITY; l_r[r] = 0.0f; }
  f32x4 accO[8] = {};

  const float scale = 0.08838834764831845f;  // 1/sqrt(128)

  for (int kv0 = 0; kv0 < 1024; kv0 += 32) {
    // S tile: 16 rows x 32 keys, two 16-key MFMA column tiles
    f32x4 s[2] = {};
#pragma unroll
    for (int kt = 0; kt < 2; ++kt) {
#pragma unroll
      for (int dc = 0; dc < 4; ++dc) {
        bf16x8 kf = *(const bf16x8*)&kbase[(size_t)(kv0 + kt * 16 + (lane & 15)) * 4096 +
                                           dc * 32 + (lane >> 4) * 8];
        s[kt] = __builtin_amdgcn_mfma_f32_16x16x32_bf16(qf[dc], kf, s[kt], 0, 0, 0);
      }
    }
    // online softmax per row r (row = (lane>>4)*4 + r, col = lane&15 within each kt tile)
#pragma unroll
    for (int r = 0; r < 4; ++r) {
      float s0 = s[0][r] * scale;
      float s1 = s[1][r] * scale;
      float mx = fmaxf(s0, s1);
#pragma unroll
      for (int off = 1; off < 16; off <<= 1) mx = fmaxf(mx, __shfl_xor(mx, off));
      float mnew = fmaxf(m_r[r], mx);
      float sc = __expf(m_r[r] - mnew);
      float p0 = __expf(s0 - mnew);
      float p1 = __expf(s1 - mnew);
      float rs = p0 + p1;
#pragma unroll
      for (int off = 1; off < 16; off <<= 1) rs += __shfl_xor(rs, off);
      l_r[r] = l_r[r] * sc + rs;
      m_r[r] = mnew;
#pragma unroll
      for (int d0 = 0; d0 < 8; ++d0) accO[d0][r] *= sc;
      int prow = (lane >> 4) * 4 + r;
      P[wid][prow][(lane & 15)] = f2bf(p0);
      P[wid][prow][16 + (lane & 15)] = f2bf(p1);
    }
    // P (C-layout) -> A-fragment via LDS (wave-local; LDS ops are in-order per wave)
    bf16x8 pf = *(const bf16x8*)&P[wid][lane & 15][(lane >> 4) * 8];
#pragma unroll
    for (int d0 = 0; d0 < 8; ++d0) {
      bf16x8 vf = *(const bf16x8*)&vbase[(size_t)(d0 * 16 + (lane & 15)) * 1024 + kv0 +
                                         (lane >> 4) * 8];
      accO[d0] = __builtin_amdgcn_mfma_f32_16x16x32_bf16(pf, vf, accO[d0], 0, 0, 0);
    }
  }

  // normalize + store att (bf16)
  float invl[4];
#pragma unroll
  for (int r = 0; r < 4; ++r) invl[r] = 1.0f / l_r[r];
#pragma unroll
  for (int d0 = 0; d0 < 8; ++d0) {
#pragma unroll
    for (int r = 0; r < 4; ++r) {
      int arow = q0 + (lane >> 4) * 4 + r;
      att[(size_t)(b * 1024 + arow) * 2048 + h * 128 + d0 * 16 + (lane & 15)] =
          f2bf(accO[d0][r] * invl[r]);
    }
  }
}

// ---------------- launch ----------------
extern "C" void kernel_launch(void* const* d_in, const int* in_sizes, int n_in,
                              void* d_out, int out_size, void* d_ws, size_t ws_size,
                              hipStream_t stream) {
  const float* x = (const float*)d_in[0];      // [4,1024,2048]
  const float* Wqkv = (const float*)d_in[1];   // [6144,2048]
  const float* bqkv = (const float*)d_in[2];   // [6144]
  const float* Wproj = (const float*)d_in[3];  // [2048,2048]
  const float* bproj = (const float*)d_in[4];  // [2048]
  // d_in[5] = noise: provably unused (imag part never reaches the real output)
  float* out = (float*)d_out;

  // workspace layout (bf16 = 2B), all sizes multiples of 256B
  char* ws = (char*)d_ws;
  short* xb = (short*)(ws + 0);                       // 4096*2048   -> 16MB
  short* Wqkvb = (short*)(ws + 16777216);             // 6144*2048   -> 25.2MB
  short* Wprojb = (short*)(ws + 41943040);             // 2048*2048   -> 8.4MB
  short* qkbuf = (short*)(ws + 50331648);             // 4096*4096   -> 33.6MB
  short* vT = (short*)(ws + 83886080);                // 4*16*128*1024 -> 16.8MB
  short* attb = (short*)(ws + 100663296);             // 4096*2048   -> 16.8MB

  hipLaunchKernelGGL(cast_f32_bf16, dim3(2048), dim3(256), 0, stream,
                     x, xb, kM * kC / 4);
  hipLaunchKernelGGL(cast_f32_bf16, dim3(2048), dim3(256), 0, stream,
                     Wqkv, Wqkvb, k3C * kC / 4);
  hipLaunchKernelGGL(cast_f32_bf16, dim3(2048), dim3(256), 0, stream,
                     Wproj, Wprojb, kC * kC / 4);

  // QKV: [4096,2048] @ [6144,2048]^T
  hipLaunchKernelGGL((gemm_bt<0>), dim3(kM / 128, k3C / 128), dim3(256), 0, stream,
                     xb, Wqkvb, bqkv, (void*)qkbuf, vT, kM, k3C, kC);

  // attention: grid (N/64, B*H)
  hipLaunchKernelGGL(attn_kernel, dim3(kN / 64, kB * kH), dim3(256), 0, stream,
                     qkbuf, vT, attb);

  // proj: [4096,2048] @ [2048,2048]^T -> fp32 out
  hipLaunchKernelGGL((gemm_bt<1>), dim3(kM / 128, kC / 128), dim3(256), 0, stream,
                     attb, Wprojb, bproj, (void*)out, (short*)nullptr, kM, kC, kC);
}

// Round 6
// 320.631 us; speedup vs baseline: 1.6257x; 1.6257x over previous
//
#include <hip/hip_runtime.h>
#include <hip/hip_bf16.h>
#include <math.h>

typedef __attribute__((ext_vector_type(8))) short bf16x8;
typedef __attribute__((ext_vector_type(4))) float f32x4;

static constexpr int kB = 4, kN = 1024, kC = 2048, kH = 16, kD = 128;
static constexpr int kM = kB * kN;   // 4096
static constexpr int k3C = 3 * kC;   // 6144

__device__ __forceinline__ short f2bf(float f) {
  unsigned u = __float_as_uint(f);
  u = (u + 0x7FFFu + ((u >> 16) & 1u)) >> 16;   // RNE
  return (short)u;
}

// ---------------- cast fp32 -> bf16 ----------------
__global__ __launch_bounds__(256) void cast_f32_bf16(const float* __restrict__ in,
                                                     short* __restrict__ out, int n4) {
  int stride = gridDim.x * blockDim.x;
  for (int i = blockIdx.x * blockDim.x + threadIdx.x; i < n4; i += stride) {
    float4 v = reinterpret_cast<const float4*>(in)[i];
    short4 o = make_short4(f2bf(v.x), f2bf(v.y), f2bf(v.z), f2bf(v.w));
    reinterpret_cast<short4*>(out)[i] = o;
  }
}

// ---------------- GEMM C[m,n] = sum_k A[m,k]*Bt[n,k] + bias[n] ----------------
template <int EPI>
__global__ __launch_bounds__(256) void gemm_bt(const short* __restrict__ A,
                                               const short* __restrict__ Bt,
                                               const float* __restrict__ bias,
                                               void* __restrict__ out0,
                                               short* __restrict__ vT,
                                               int M, int N, int K) {
  __shared__ short As[128 * 32];
  __shared__ short Bs[128 * 32];
  const int lane = threadIdx.x & 63;
  const int wid = threadIdx.x >> 6;
  const int row0 = blockIdx.x * 128;
  const int col0 = blockIdx.y * 128;
  const int wrow = (wid >> 1) * 64;
  const int wcol = (wid & 1) * 64;
  f32x4 acc[4][4] = {};

  const short* Ag0 = A + (size_t)(row0 + wid * 32 + (lane >> 2)) * K + (lane & 3) * 8;
  const short* Bg0 = Bt + (size_t)(col0 + wid * 32 + (lane >> 2)) * K + (lane & 3) * 8;

  for (int k0 = 0; k0 < K; k0 += 32) {
    __builtin_amdgcn_global_load_lds(
        (const __attribute__((address_space(1))) void*)(Ag0 + k0),
        (__attribute__((address_space(3))) void*)&As[(wid * 32) * 32], 16, 0, 0);
    __builtin_amdgcn_global_load_lds(
        (const __attribute__((address_space(1))) void*)(Ag0 + 16 * (size_t)K + k0),
        (__attribute__((address_space(3))) void*)&As[(wid * 32 + 16) * 32], 16, 0, 0);
    __builtin_amdgcn_global_load_lds(
        (const __attribute__((address_space(1))) void*)(Bg0 + k0),
        (__attribute__((address_space(3))) void*)&Bs[(wid * 32) * 32], 16, 0, 0);
    __builtin_amdgcn_global_load_lds(
        (const __attribute__((address_space(1))) void*)(Bg0 + 16 * (size_t)K + k0),
        (__attribute__((address_space(3))) void*)&Bs[(wid * 32 + 16) * 32], 16, 0, 0);
    __syncthreads();

    bf16x8 af[4], bfr[4];
#pragma unroll
    for (int mt = 0; mt < 4; ++mt)
      af[mt] = *(const bf16x8*)&As[(wrow + mt * 16 + (lane & 15)) * 32 + (lane >> 4) * 8];
#pragma unroll
    for (int nt = 0; nt < 4; ++nt)
      bfr[nt] = *(const bf16x8*)&Bs[(wcol + nt * 16 + (lane & 15)) * 32 + (lane >> 4) * 8];
#pragma unroll
    for (int mt = 0; mt < 4; ++mt)
#pragma unroll
      for (int nt = 0; nt < 4; ++nt)
        acc[mt][nt] = __builtin_amdgcn_mfma_f32_16x16x32_bf16(af[mt], bfr[nt], acc[mt][nt], 0, 0, 0);
    __syncthreads();
  }

  if (EPI == 0) {
    short* qk = (short*)out0;
#pragma unroll
    for (int mt = 0; mt < 4; ++mt) {
#pragma unroll
      for (int nt = 0; nt < 4; ++nt) {
        int col = col0 + wcol + nt * 16 + (lane & 15);
        float bv = bias[col];
#pragma unroll
        for (int r = 0; r < 4; ++r) {
          int row = row0 + wrow + mt * 16 + (lane >> 4) * 4 + r;
          float v = acc[mt][nt][r] + bv;
          if (col < 4096) {
            qk[(size_t)row * 4096 + col] = f2bf(v);
          } else {
            int b = row >> 10, pos = row & 1023;
            int hd = col - 4096;
            vT[((size_t)b * 2048 + hd) * 1024 + pos] = f2bf(v);
          }
        }
      }
    }
  } else {
    float* out = (float*)out0;
#pragma unroll
    for (int mt = 0; mt < 4; ++mt) {
#pragma unroll
      for (int nt = 0; nt < 4; ++nt) {
        int col = col0 + wcol + nt * 16 + (lane & 15);
        float bv = bias[col];
#pragma unroll
        for (int r = 0; r < 4; ++r) {
          int row = row0 + wrow + mt * 16 + (lane >> 4) * 4 + r;
          out[(size_t)row * N + col] = acc[mt][nt][r] + bv;
        }
      }
    }
  }
}

// ---------------- flash attention v2: LDS-staged K/V, double-buffered ----------------
// grid: (N/64, B*H). 4 waves; wave w owns 16 q-rows. KVBLK=64.
// K tile Ks[buf][64][128] shorts, XOR-swizzled: LDS[r][x] = K[r][x ^ ((r&7)<<4)] (byte idx).
// V tile Vs[buf][128][64] shorts (row=d, col=pos), same swizzle per d-row.
// Staged via global_load_lds w=16 with pre-swizzled global source (rule 21).
__global__ __launch_bounds__(256) void attn_kernel(const short* __restrict__ qk,
                                                   const short* __restrict__ vT,
                                                   short* __restrict__ att) {
  __shared__ __align__(16) short Ks[2][64][128];   // 2 x 16 KB
  __shared__ __align__(16) short Vs[2][128][64];   // 2 x 16 KB
  __shared__ __align__(16) short P[4][16][72];     // 9 KB, stride 72 for bank spread
  const int lane = threadIdx.x & 63;
  const int wid = threadIdx.x >> 6;
  const int bh = blockIdx.y;
  const int b = bh >> 4, h = bh & 15;
  const int q0 = blockIdx.x * 64 + wid * 16;

  const short* qbase = qk + (size_t)(b * 1024) * 4096 + h * 128;
  const short* kglob = qbase + 2048;
  const short* vglob = vT + (size_t)bh * 128 * 1024;

  // hoist Q fragments (16 rows x 128 d)
  bf16x8 qf[4];
  {
    const int qrow = q0 + (lane & 15);
#pragma unroll
    for (int dc = 0; dc < 4; ++dc)
      qf[dc] = *(const bf16x8*)&qbase[(size_t)qrow * 4096 + dc * 32 + (lane >> 4) * 8];
  }

  // precompute per-lane staging source components
  const int krow_l = wid * 16 + (lane >> 4);          // +4*i
  const int kcol_l = (lane & 15) << 4;                // byte col before swizzle
  const int vrow_l = wid * 32 + (lane >> 3);          // +8*i
  const int vcol_l = (lane & 7) << 4;

#define STAGE_KV(buf, kv0)                                                              \
  {                                                                                     \
    _Pragma("unroll") for (int i = 0; i < 4; ++i) {                                     \
      int r = krow_l + i * 4;                                                           \
      const char* src = (const char*)(kglob + (size_t)((kv0) + r) * 4096) +             \
                        (kcol_l ^ ((r & 7) << 4));                                      \
      __builtin_amdgcn_global_load_lds(                                                 \
          (const __attribute__((address_space(1))) void*)src,                           \
          (__attribute__((address_space(3))) void*)&Ks[buf][wid * 16 + i * 4][0], 16,   \
          0, 0);                                                                        \
    }                                                                                   \
    _Pragma("unroll") for (int i = 0; i < 4; ++i) {                                     \
      int d = vrow_l + i * 8;                                                           \
      const char* src = (const char*)(vglob + (size_t)d * 1024 + (kv0)) +               \
                        (vcol_l ^ ((d & 7) << 4));                                      \
      __builtin_amdgcn_global_load_lds(                                                 \
          (const __attribute__((address_space(1))) void*)src,                           \
          (__attribute__((address_space(3))) void*)&Vs[buf][wid * 32 + i * 8][0], 16,   \
          0, 0);                                                                        \
    }                                                                                   \
  }

  float m_r[4], l_r[4];
#pragma unroll
  for (int r = 0; r < 4; ++r) { m_r[r] = -INFINITY; l_r[r] = 0.0f; }
  f32x4 accO[8] = {};

  const float scale = 0.08838834764831845f;  // 1/sqrt(128)

  // prologue
  STAGE_KV(0, 0);
  asm volatile("s_waitcnt vmcnt(0)" ::: "memory");
  __builtin_amdgcn_s_barrier();
  __builtin_amdgcn_sched_barrier(0);

  int cur = 0;
  for (int t = 0; t < 16; ++t) {
    if (t < 15) STAGE_KV(cur ^ 1, (t + 1) * 64);

    // ---- QK^T: 16 rows x 64 keys ----
    f32x4 s4[4] = {};
#pragma unroll
    for (int kt = 0; kt < 4; ++kt) {
      const int row = kt * 16 + (lane & 15);
      const char* kr = (const char*)&Ks[cur][row][0];
      const int swz = (row & 7) << 4;
#pragma unroll
      for (int dc = 0; dc < 4; ++dc) {
        bf16x8 kf = *(const bf16x8*)(kr + ((dc * 64 + (lane >> 4) * 16) ^ swz));
        s4[kt] = __builtin_amdgcn_mfma_f32_16x16x32_bf16(qf[dc], kf, s4[kt], 0, 0, 0);
      }
    }

    // ---- online softmax ----
#pragma unroll
    for (int r = 0; r < 4; ++r) {
      float sv0 = s4[0][r] * scale, sv1 = s4[1][r] * scale;
      float sv2 = s4[2][r] * scale, sv3 = s4[3][r] * scale;
      float mx = fmaxf(fmaxf(sv0, sv1), fmaxf(sv2, sv3));
#pragma unroll
      for (int off = 1; off < 16; off <<= 1) mx = fmaxf(mx, __shfl_xor(mx, off));
      float mnew = fmaxf(m_r[r], mx);
      float sc = __expf(m_r[r] - mnew);
      float p0 = __expf(sv0 - mnew), p1 = __expf(sv1 - mnew);
      float p2 = __expf(sv2 - mnew), p3 = __expf(sv3 - mnew);
      float rs = (p0 + p1) + (p2 + p3);
#pragma unroll
      for (int off = 1; off < 16; off <<= 1) rs += __shfl_xor(rs, off);
      l_r[r] = l_r[r] * sc + rs;
      m_r[r] = mnew;
#pragma unroll
      for (int d0 = 0; d0 < 8; ++d0) accO[d0][r] *= sc;
      int prow = (lane >> 4) * 4 + r;
      P[wid][prow][(lane & 15)] = f2bf(p0);
      P[wid][prow][16 + (lane & 15)] = f2bf(p1);
      P[wid][prow][32 + (lane & 15)] = f2bf(p2);
      P[wid][prow][48 + (lane & 15)] = f2bf(p3);
    }

    // P (C-layout) -> A-fragments (wave-local; LDS ops in-order per wave)
    bf16x8 pf0 = *(const bf16x8*)&P[wid][lane & 15][(lane >> 4) * 8];
    bf16x8 pf1 = *(const bf16x8*)&P[wid][lane & 15][32 + (lane >> 4) * 8];

    // ---- PV ----
#pragma unroll
    for (int d0 = 0; d0 < 8; ++d0) {
      const int d = d0 * 16 + (lane & 15);
      const char* vr = (const char*)&Vs[cur][d][0];
      const int swz = (d & 7) << 4;
      bf16x8 vf0 = *(const bf16x8*)(vr + (((lane >> 4) * 16) ^ swz));
      bf16x8 vf1 = *(const bf16x8*)(vr + ((64 + (lane >> 4) * 16) ^ swz));
      accO[d0] = __builtin_amdgcn_mfma_f32_16x16x32_bf16(pf0, vf0, accO[d0], 0, 0, 0);
      accO[d0] = __builtin_amdgcn_mfma_f32_16x16x32_bf16(pf1, vf1, accO[d0], 0, 0, 0);
    }

    asm volatile("s_waitcnt vmcnt(0)" ::: "memory");
    __builtin_amdgcn_s_barrier();
    __builtin_amdgcn_sched_barrier(0);
    cur ^= 1;
  }
#undef STAGE_KV

  // normalize + store att (bf16)
  float invl[4];
#pragma unroll
  for (int r = 0; r < 4; ++r) invl[r] = 1.0f / l_r[r];
#pragma unroll
  for (int d0 = 0; d0 < 8; ++d0) {
#pragma unroll
    for (int r = 0; r < 4; ++r) {
      int arow = q0 + (lane >> 4) * 4 + r;
      att[(size_t)(b * 1024 + arow) * 2048 + h * 128 + d0 * 16 + (lane & 15)] =
          f2bf(accO[d0][r] * invl[r]);
    }
  }
}

// ---------------- launch ----------------
extern "C" void kernel_launch(void* const* d_in, const int* in_sizes, int n_in,
                              void* d_out, int out_size, void* d_ws, size_t ws_size,
                              hipStream_t stream) {
  const float* x = (const float*)d_in[0];
  const float* Wqkv = (const float*)d_in[1];
  const float* bqkv = (const float*)d_in[2];
  const float* Wproj = (const float*)d_in[3];
  const float* bproj = (const float*)d_in[4];
  // d_in[5] = noise: provably unused (imag part never reaches the real output)
  float* out = (float*)d_out;

  char* ws = (char*)d_ws;
  short* xb = (short*)(ws + 0);
  short* Wqkvb = (short*)(ws + 16777216);
  short* Wprojb = (short*)(ws + 41943040);
  short* qkbuf = (short*)(ws + 50331648);
  short* vT = (short*)(ws + 83886080);
  short* attb = (short*)(ws + 100663296);

  hipLaunchKernelGGL(cast_f32_bf16, dim3(2048), dim3(256), 0, stream,
                     x, xb, kM * kC / 4);
  hipLaunchKernelGGL(cast_f32_bf16, dim3(2048), dim3(256), 0, stream,
                     Wqkv, Wqkvb, k3C * kC / 4);
  hipLaunchKernelGGL(cast_f32_bf16, dim3(2048), dim3(256), 0, stream,
                     Wproj, Wprojb, kC * kC / 4);

  hipLaunchKernelGGL((gemm_bt<0>), dim3(kM / 128, k3C / 128), dim3(256), 0, stream,
                     xb, Wqkvb, bqkv, (void*)qkbuf, vT, kM, k3C, kC);

  hipLaunchKernelGGL(attn_kernel, dim3(kN / 64, kB * kH), dim3(256), 0, stream,
                     qkbuf, vT, attb);

  hipLaunchKernelGGL((gemm_bt<1>), dim3(kM / 128, kC / 128), dim3(256), 0, stream,
                     attb, Wprojb, bproj, (void*)out, (short*)nullptr, kM, kC, kC);
}

// Round 7
// 302.329 us; speedup vs baseline: 1.7241x; 1.0605x over previous
//
#include <hip/hip_runtime.h>
#include <hip/hip_bf16.h>
#include <math.h>

typedef __attribute__((ext_vector_type(8))) short bf16x8;
typedef __attribute__((ext_vector_type(4))) float f32x4;

static constexpr int kB = 4, kN = 1024, kC = 2048, kH = 16, kD = 128;
static constexpr int kM = kB * kN;   // 4096
static constexpr int k3C = 3 * kC;   // 6144

__device__ __forceinline__ short f2bf(float f) {
  unsigned u = __float_as_uint(f);
  u = (u + 0x7FFFu + ((u >> 16) & 1u)) >> 16;   // RNE
  return (short)u;
}

// ---------------- cast fp32 -> bf16 ----------------
__global__ __launch_bounds__(256) void cast_f32_bf16(const float* __restrict__ in,
                                                     short* __restrict__ out, int n4) {
  int stride = gridDim.x * blockDim.x;
  for (int i = blockIdx.x * blockDim.x + threadIdx.x; i < n4; i += stride) {
    float4 v = reinterpret_cast<const float4*>(in)[i];
    short4 o = make_short4(f2bf(v.x), f2bf(v.y), f2bf(v.z), f2bf(v.w));
    reinterpret_cast<short4*>(out)[i] = o;
  }
}

// ---------------- GEMM C[m,n] = sum_k A[m,k]*Bt[n,k] + bias[n] ----------------
// 2-phase double-buffered (T3 minimum): STAGE(t+1) || compute(t), one barrier/K-step.
template <int EPI>
__global__ __launch_bounds__(256) void gemm_bt(const short* __restrict__ A,
                                               const short* __restrict__ Bt,
                                               const float* __restrict__ bias,
                                               void* __restrict__ out0,
                                               short* __restrict__ vT,
                                               int M, int N, int K) {
  __shared__ short As[2][128 * 32];
  __shared__ short Bs[2][128 * 32];
  const int lane = threadIdx.x & 63;
  const int wid = threadIdx.x >> 6;
  const int row0 = blockIdx.x * 128;
  const int col0 = blockIdx.y * 128;
  const int wrow = (wid >> 1) * 64;
  const int wcol = (wid & 1) * 64;
  f32x4 acc[4][4] = {};

  const short* Ag0 = A + (size_t)(row0 + wid * 32 + (lane >> 2)) * K + (lane & 3) * 8;
  const short* Bg0 = Bt + (size_t)(col0 + wid * 32 + (lane >> 2)) * K + (lane & 3) * 8;

#define GSTAGE(buf, k0)                                                                 \
  {                                                                                     \
    __builtin_amdgcn_global_load_lds(                                                   \
        (const __attribute__((address_space(1))) void*)(Ag0 + (k0)),                    \
        (__attribute__((address_space(3))) void*)&As[buf][(wid * 32) * 32], 16, 0, 0);  \
    __builtin_amdgcn_global_load_lds(                                                   \
        (const __attribute__((address_space(1))) void*)(Ag0 + 16 * (size_t)K + (k0)),   \
        (__attribute__((address_space(3))) void*)&As[buf][(wid * 32 + 16) * 32], 16, 0, \
        0);                                                                             \
    __builtin_amdgcn_global_load_lds(                                                   \
        (const __attribute__((address_space(1))) void*)(Bg0 + (k0)),                    \
        (__attribute__((address_space(3))) void*)&Bs[buf][(wid * 32) * 32], 16, 0, 0);  \
    __builtin_amdgcn_global_load_lds(                                                   \
        (const __attribute__((address_space(1))) void*)(Bg0 + 16 * (size_t)K + (k0)),   \
        (__attribute__((address_space(3))) void*)&Bs[buf][(wid * 32 + 16) * 32], 16, 0, \
        0);                                                                             \
  }

  GSTAGE(0, 0);
  __syncthreads();   // compiler emits vmcnt(0) lgkmcnt(0) drain + barrier

  int cur = 0;
  for (int k0 = 0; k0 < K; k0 += 32) {
    if (k0 + 32 < K) GSTAGE(cur ^ 1, k0 + 32);   // overlap with compute below

    bf16x8 af[4], bfr[4];
#pragma unroll
    for (int mt = 0; mt < 4; ++mt)
      af[mt] = *(const bf16x8*)&As[cur][(wrow + mt * 16 + (lane & 15)) * 32 + (lane >> 4) * 8];
#pragma unroll
    for (int nt = 0; nt < 4; ++nt)
      bfr[nt] = *(const bf16x8*)&Bs[cur][(wcol + nt * 16 + (lane & 15)) * 32 + (lane >> 4) * 8];
#pragma unroll
    for (int mt = 0; mt < 4; ++mt)
#pragma unroll
      for (int nt = 0; nt < 4; ++nt)
        acc[mt][nt] = __builtin_amdgcn_mfma_f32_16x16x32_bf16(af[mt], bfr[nt], acc[mt][nt], 0, 0, 0);

    __syncthreads();   // drains this iter's STAGE loads (issued a full compute phase ago)
    cur ^= 1;
  }
#undef GSTAGE

  if (EPI == 0) {
    short* qk = (short*)out0;
#pragma unroll
    for (int mt = 0; mt < 4; ++mt) {
#pragma unroll
      for (int nt = 0; nt < 4; ++nt) {
        int col = col0 + wcol + nt * 16 + (lane & 15);
        float bv = bias[col];
#pragma unroll
        for (int r = 0; r < 4; ++r) {
          int row = row0 + wrow + mt * 16 + (lane >> 4) * 4 + r;
          float v = acc[mt][nt][r] + bv;
          if (col < 4096) {
            qk[(size_t)row * 4096 + col] = f2bf(v);
          } else {
            int b = row >> 10, pos = row & 1023;
            int hd = col - 4096;
            vT[((size_t)b * 2048 + hd) * 1024 + pos] = f2bf(v);
          }
        }
      }
    }
  } else {
    float* out = (float*)out0;
#pragma unroll
    for (int mt = 0; mt < 4; ++mt) {
#pragma unroll
      for (int nt = 0; nt < 4; ++nt) {
        int col = col0 + wcol + nt * 16 + (lane & 15);
        float bv = bias[col];
#pragma unroll
        for (int r = 0; r < 4; ++r) {
          int row = row0 + wrow + mt * 16 + (lane >> 4) * 4 + r;
          out[(size_t)row * N + col] = acc[mt][nt][r] + bv;
        }
      }
    }
  }
}

// ---------------- flash attention v2: LDS-staged K/V, double-buffered ----------------
__global__ __launch_bounds__(256) void attn_kernel(const short* __restrict__ qk,
                                                   const short* __restrict__ vT,
                                                   short* __restrict__ att) {
  __shared__ __align__(16) short Ks[2][64][128];   // 2 x 16 KB
  __shared__ __align__(16) short Vs[2][128][64];   // 2 x 16 KB
  __shared__ __align__(16) short P[4][16][72];     // 9 KB, stride 72 for bank spread
  const int lane = threadIdx.x & 63;
  const int wid = threadIdx.x >> 6;
  const int bh = blockIdx.y;
  const int b = bh >> 4, h = bh & 15;
  const int q0 = blockIdx.x * 64 + wid * 16;

  const short* qbase = qk + (size_t)(b * 1024) * 4096 + h * 128;
  const short* kglob = qbase + 2048;
  const short* vglob = vT + (size_t)bh * 128 * 1024;

  bf16x8 qf[4];
  {
    const int qrow = q0 + (lane & 15);
#pragma unroll
    for (int dc = 0; dc < 4; ++dc)
      qf[dc] = *(const bf16x8*)&qbase[(size_t)qrow * 4096 + dc * 32 + (lane >> 4) * 8];
  }

  const int krow_l = wid * 16 + (lane >> 4);
  const int kcol_l = (lane & 15) << 4;
  const int vrow_l = wid * 32 + (lane >> 3);
  const int vcol_l = (lane & 7) << 4;

#define STAGE_KV(buf, kv0)                                                              \
  {                                                                                     \
    _Pragma("unroll") for (int i = 0; i < 4; ++i) {                                     \
      int r = krow_l + i * 4;                                                           \
      const char* src = (const char*)(kglob + (size_t)((kv0) + r) * 4096) +             \
                        (kcol_l ^ ((r & 7) << 4));                                      \
      __builtin_amdgcn_global_load_lds(                                                 \
          (const __attribute__((address_space(1))) void*)src,                           \
          (__attribute__((address_space(3))) void*)&Ks[buf][wid * 16 + i * 4][0], 16,   \
          0, 0);                                                                        \
    }                                                                                   \
    _Pragma("unroll") for (int i = 0; i < 4; ++i) {                                     \
      int d = vrow_l + i * 8;                                                           \
      const char* src = (const char*)(vglob + (size_t)d * 1024 + (kv0)) +               \
                        (vcol_l ^ ((d & 7) << 4));                                      \
      __builtin_amdgcn_global_load_lds(                                                 \
          (const __attribute__((address_space(1))) void*)src,                           \
          (__attribute__((address_space(3))) void*)&Vs[buf][wid * 32 + i * 8][0], 16,   \
          0, 0);                                                                        \
    }                                                                                   \
  }

  float m_r[4], l_r[4];
#pragma unroll
  for (int r = 0; r < 4; ++r) { m_r[r] = -INFINITY; l_r[r] = 0.0f; }
  f32x4 accO[8] = {};

  const float scale = 0.08838834764831845f;  // 1/sqrt(128)

  STAGE_KV(0, 0);
  asm volatile("s_waitcnt vmcnt(0)" ::: "memory");
  __builtin_amdgcn_s_barrier();
  __builtin_amdgcn_sched_barrier(0);

  int cur = 0;
  for (int t = 0; t < 16; ++t) {
    if (t < 15) STAGE_KV(cur ^ 1, (t + 1) * 64);

    f32x4 s4[4] = {};
#pragma unroll
    for (int kt = 0; kt < 4; ++kt) {
      const int row = kt * 16 + (lane & 15);
      const char* kr = (const char*)&Ks[cur][row][0];
      const int swz = (row & 7) << 4;
#pragma unroll
      for (int dc = 0; dc < 4; ++dc) {
        bf16x8 kf = *(const bf16x8*)(kr + ((dc * 64 + (lane >> 4) * 16) ^ swz));
        s4[kt] = __builtin_amdgcn_mfma_f32_16x16x32_bf16(qf[dc], kf, s4[kt], 0, 0, 0);
      }
    }

#pragma unroll
    for (int r = 0; r < 4; ++r) {
      float sv0 = s4[0][r] * scale, sv1 = s4[1][r] * scale;
      float sv2 = s4[2][r] * scale, sv3 = s4[3][r] * scale;
      float mx = fmaxf(fmaxf(sv0, sv1), fmaxf(sv2, sv3));
#pragma unroll
      for (int off = 1; off < 16; off <<= 1) mx = fmaxf(mx, __shfl_xor(mx, off));
      float mnew = fmaxf(m_r[r], mx);
      float sc = __expf(m_r[r] - mnew);
      float p0 = __expf(sv0 - mnew), p1 = __expf(sv1 - mnew);
      float p2 = __expf(sv2 - mnew), p3 = __expf(sv3 - mnew);
      float rs = (p0 + p1) + (p2 + p3);
#pragma unroll
      for (int off = 1; off < 16; off <<= 1) rs += __shfl_xor(rs, off);
      l_r[r] = l_r[r] * sc + rs;
      m_r[r] = mnew;
#pragma unroll
      for (int d0 = 0; d0 < 8; ++d0) accO[d0][r] *= sc;
      int prow = (lane >> 4) * 4 + r;
      P[wid][prow][(lane & 15)] = f2bf(p0);
      P[wid][prow][16 + (lane & 15)] = f2bf(p1);
      P[wid][prow][32 + (lane & 15)] = f2bf(p2);
      P[wid][prow][48 + (lane & 15)] = f2bf(p3);
    }

    bf16x8 pf0 = *(const bf16x8*)&P[wid][lane & 15][(lane >> 4) * 8];
    bf16x8 pf1 = *(const bf16x8*)&P[wid][lane & 15][32 + (lane >> 4) * 8];

#pragma unroll
    for (int d0 = 0; d0 < 8; ++d0) {
      const int d = d0 * 16 + (lane & 15);
      const char* vr = (const char*)&Vs[cur][d][0];
      const int swz = (d & 7) << 4;
      bf16x8 vf0 = *(const bf16x8*)(vr + (((lane >> 4) * 16) ^ swz));
      bf16x8 vf1 = *(const bf16x8*)(vr + ((64 + (lane >> 4) * 16) ^ swz));
      accO[d0] = __builtin_amdgcn_mfma_f32_16x16x32_bf16(pf0, vf0, accO[d0], 0, 0, 0);
      accO[d0] = __builtin_amdgcn_mfma_f32_16x16x32_bf16(pf1, vf1, accO[d0], 0, 0, 0);
    }

    asm volatile("s_waitcnt vmcnt(0)" ::: "memory");
    __builtin_amdgcn_s_barrier();
    __builtin_amdgcn_sched_barrier(0);
    cur ^= 1;
  }
#undef STAGE_KV

  float invl[4];
#pragma unroll
  for (int r = 0; r < 4; ++r) invl[r] = 1.0f / l_r[r];
#pragma unroll
  for (int d0 = 0; d0 < 8; ++d0) {
#pragma unroll
    for (int r = 0; r < 4; ++r) {
      int arow = q0 + (lane >> 4) * 4 + r;
      att[(size_t)(b * 1024 + arow) * 2048 + h * 128 + d0 * 16 + (lane & 15)] =
          f2bf(accO[d0][r] * invl[r]);
    }
  }
}

// ---------------- launch ----------------
extern "C" void kernel_launch(void* const* d_in, const int* in_sizes, int n_in,
                              void* d_out, int out_size, void* d_ws, size_t ws_size,
                              hipStream_t stream) {
  const float* x = (const float*)d_in[0];
  const float* Wqkv = (const float*)d_in[1];
  const float* bqkv = (const float*)d_in[2];
  const float* Wproj = (const float*)d_in[3];
  const float* bproj = (const float*)d_in[4];
  // d_in[5] = noise: provably unused (imag part never reaches the real output)
  float* out = (float*)d_out;

  char* ws = (char*)d_ws;
  short* xb = (short*)(ws + 0);
  short* Wqkvb = (short*)(ws + 16777216);
  short* Wprojb = (short*)(ws + 41943040);
  short* qkbuf = (short*)(ws + 50331648);
  short* vT = (short*)(ws + 83886080);
  short* attb = (short*)(ws + 100663296);

  hipLaunchKernelGGL(cast_f32_bf16, dim3(2048), dim3(256), 0, stream,
                     x, xb, kM * kC / 4);
  hipLaunchKernelGGL(cast_f32_bf16, dim3(2048), dim3(256), 0, stream,
                     Wqkv, Wqkvb, k3C * kC / 4);
  hipLaunchKernelGGL(cast_f32_bf16, dim3(2048), dim3(256), 0, stream,
                     Wproj, Wprojb, kC * kC / 4);

  hipLaunchKernelGGL((gemm_bt<0>), dim3(kM / 128, k3C / 128), dim3(256), 0, stream,
                     xb, Wqkvb, bqkv, (void*)qkbuf, vT, kM, k3C, kC);

  hipLaunchKernelGGL(attn_kernel, dim3(kN / 64, kB * kH), dim3(256), 0, stream,
                     qkbuf, vT, attb);

  hipLaunchKernelGGL((gemm_bt<1>), dim3(kM / 128, kC / 128), dim3(256), 0, stream,
                     attb, Wprojb, bproj, (void*)out, (short*)nullptr, kM, kC, kC);
}